// Round 1
// baseline (3618.916 us; speedup 1.0000x reference)
//
#include <hip/hip_runtime.h>

#define Tt 256
#define Uu 1024
#define Bb 64
#define Dd 512

// ---------------- block reduction helper ----------------
__device__ __forceinline__ float blk_sum(float v, float* sm, int tid) {
#pragma unroll
    for (int o = 32; o > 0; o >>= 1) v += __shfl_down(v, o);
    if ((tid & 63) == 0) sm[tid >> 6] = v;
    __syncthreads();
    return sm[0] + sm[1] + sm[2] + sm[3];
}

// ---------------- prep: kernel_current [D,U] ----------------
__global__ __launch_bounds__(256) void prep_kc(const float* __restrict__ W,
        const float* __restrict__ mu, const float* __restrict__ sigma,
        float* __restrict__ Kc) {
    __shared__ float sm[4];
    const int u = blockIdx.x, tid = threadIdx.x;
    const float m = mu[u];
    const float si = fminf(fmaxf(sigma[u], 0.01f), 1.0f);
    const float inv = 1.0f / (2.0f * si * si);
    const float x0 = tid * (1.0f / 511.0f) - m;
    const float x1 = (tid + 256) * (1.0f / 511.0f) - m;
    const float e0 = expf(-x0 * x0 * inv);
    const float e1 = expf(-x1 * x1 * inv);
    const float s = blk_sum(e0 * e0 + e1 * e1, sm, tid);
    const float scale = sqrtf(512.0f) / sqrtf(s);
    Kc[tid * Uu + u]         = W[tid * Uu + u] * e0 * scale;
    Kc[(tid + 256) * Uu + u] = W[(tid + 256) * Uu + u] * e1 * scale;
}

// ---------------- prep: kernel_previous, transposed+blocked ----------------
// KpT layout: idx(u,k) = ((u>>5)*256 + (k>>2))*128 + (u&31)*4 + (k&3)
__global__ __launch_bounds__(256) void prep_kp(const float* __restrict__ W,
        const float* __restrict__ mu, const float* __restrict__ sigma,
        float* __restrict__ KpT) {
    __shared__ float sm[4];
    const int u = blockIdx.x, tid = threadIdx.x;
    const float m = mu[u];
    const float si = fminf(fmaxf(sigma[u], 0.01f), 1.0f);
    const float inv = 1.0f / (2.0f * si * si);
    float e[4];
    float s = 0.f;
#pragma unroll
    for (int i = 0; i < 4; i++) {
        const int k = tid + 256 * i;
        const float x = k * (1.0f / 1023.0f) - m;
        e[i] = expf(-x * x * inv);
        s += e[i] * e[i];
    }
    s = blk_sum(s, sm, tid);
    const float scale = sqrtf(512.0f) / sqrtf(s);  // input_dim = 512 for BOTH masks (per source)
#pragma unroll
    for (int i = 0; i < 4; i++) {
        const int k = tid + 256 * i;
        const float v = W[k * Uu + u] * e[i] * scale;
        KpT[((u >> 5) * 256 + (k >> 2)) * 128 + (u & 31) * 4 + (k & 3)] = v;
    }
}

// ---------------- xk = x @ Kc  (fp32 tiled GEMM) ----------------
// M=16384 (b*T+t), N=1024, K=512. 64x64 tile, BK=16, 256 thr, 4x4/thread.
__global__ __launch_bounds__(256) void gemm_xk(const float* __restrict__ A,
        const float* __restrict__ Bm, float* __restrict__ C) {
    __shared__ float As[16][64];   // transposed: As[k][m]
    __shared__ float Bs[16][64];
    const int tid = threadIdx.x;
    const int m0 = blockIdx.y * 64, n0 = blockIdx.x * 64;
    const int tm = tid >> 4, tn = tid & 15;
    const int a_m = tid >> 2, a_k = (tid & 3) << 2;
    const int b_k = tid >> 4, b_n = (tid & 15) << 2;
    float acc[4][4] = {};
    for (int kc = 0; kc < Dd; kc += 16) {
        const float4 av = *(const float4*)&A[(m0 + a_m) * Dd + kc + a_k];
        const float4 bv = *(const float4*)&Bm[(b_k + kc) * Uu + n0 + b_n];
        __syncthreads();
        As[a_k + 0][a_m] = av.x;
        As[a_k + 1][a_m] = av.y;
        As[a_k + 2][a_m] = av.z;
        As[a_k + 3][a_m] = av.w;
        *(float4*)&Bs[b_k][b_n] = bv;
        __syncthreads();
#pragma unroll
        for (int kk = 0; kk < 16; kk++) {
            const float4 a4 = *(const float4*)&As[kk][tm * 4];
            const float4 b4 = *(const float4*)&Bs[kk][tn * 4];
            acc[0][0] += a4.x * b4.x; acc[0][1] += a4.x * b4.y; acc[0][2] += a4.x * b4.z; acc[0][3] += a4.x * b4.w;
            acc[1][0] += a4.y * b4.x; acc[1][1] += a4.y * b4.y; acc[1][2] += a4.y * b4.z; acc[1][3] += a4.y * b4.w;
            acc[2][0] += a4.z * b4.x; acc[2][1] += a4.z * b4.y; acc[2][2] += a4.z * b4.z; acc[2][3] += a4.z * b4.w;
            acc[3][0] += a4.w * b4.x; acc[3][1] += a4.w * b4.y; acc[3][2] += a4.w * b4.z; acc[3][3] += a4.w * b4.w;
        }
    }
#pragma unroll
    for (int i = 0; i < 4; i++) {
        const float4 o = make_float4(acc[i][0], acc[i][1], acc[i][2], acc[i][3]);
        *(float4*)&C[(long)(m0 + tm * 4 + i) * Uu + n0 + tn * 4] = o;
    }
}

// ---------------- one recurrence step: out[:,t,:] += h_prev @ Kp ----------------
// grid (32 ugrp, 8 bgrp), 256 thr; tile [8 b x 32 u]; 1 output/thread.
__global__ __launch_bounds__(256) void step_kernel(const float* __restrict__ hprev,
        long hstride, const float* __restrict__ KpT, float* __restrict__ out, int t) {
    __shared__ float hs[8][1024];
    const int tid = threadIdx.x;
    const int ug = blockIdx.x;   // 0..31
    const int bg = blockIdx.y;   // 0..7
#pragma unroll
    for (int i = 0; i < 8; i++) {
        const float4 v = *(const float4*)&hprev[(long)(bg * 8 + i) * hstride + tid * 4];
        *(float4*)&hs[i][tid * 4] = v;
    }
    __syncthreads();
    const int u_l = tid & 31, b_l = tid >> 5;
    const float* kp = KpT + (long)(ug * 256) * 128 + u_l * 4;
    const float* hrow = hs[b_l];
    float acc = 0.f;
#pragma unroll 4
    for (int kb = 0; kb < 256; kb++) {
        const float4 h4 = *(const float4*)&hrow[kb * 4];
        const float4 k4 = *(const float4*)&kp[(long)kb * 128];
        acc += h4.x * k4.x + h4.y * k4.y + h4.z * k4.z + h4.w * k4.w;
    }
    const long o = ((long)(bg * 8 + b_l) * Tt + t) * Uu + ug * 32 + u_l;
    out[o] += acc;
}

extern "C" void kernel_launch(void* const* d_in, const int* in_sizes, int n_in,
                              void* d_out, int out_size, void* d_ws, size_t ws_size,
                              hipStream_t stream) {
    const float* x      = (const float*)d_in[0];
    const float* h0     = (const float*)d_in[1];
    const float* Wc     = (const float*)d_in[2];
    const float* Wp     = (const float*)d_in[3];
    const float* mu_c   = (const float*)d_in[4];
    const float* sig_c  = (const float*)d_in[5];
    const float* mu_p   = (const float*)d_in[6];
    const float* sig_p  = (const float*)d_in[7];
    float* out = (float*)d_out;

    float* Kc  = (float*)d_ws;              // 512*1024 floats = 2 MB
    float* KpT = Kc + (size_t)Dd * Uu;      // 1024*1024 floats = 4 MB

    prep_kc<<<dim3(Uu), dim3(256), 0, stream>>>(Wc, mu_c, sig_c, Kc);
    prep_kp<<<dim3(Uu), dim3(256), 0, stream>>>(Wp, mu_p, sig_p, KpT);

    // xk = x @ Kc  -> written into d_out (in-place updated by steps)
    gemm_xk<<<dim3(Uu / 64, (Bb * Tt) / 64), dim3(256), 0, stream>>>(x, Kc, out);

    for (int t = 0; t < Tt; t++) {
        const float* hp = (t == 0) ? h0 : (const float*)(out + (long)(t - 1) * Uu);
        const long hstr = (t == 0) ? (long)Uu : (long)Tt * Uu;
        step_kernel<<<dim3(32, 8), dim3(256), 0, stream>>>(hp, hstr, KpT, out, t);
    }
}

// Round 6
// 2316.161 us; speedup vs baseline: 1.5625x; 1.5625x over previous
//
#include <hip/hip_runtime.h>

#define Tt 256
#define Uu 1024
#define Bb 64
#define Dd 512

// ---------------- block reduction helper ----------------
__device__ __forceinline__ float blk_sum(float v, float* sm, int tid) {
#pragma unroll
    for (int o = 32; o > 0; o >>= 1) v += __shfl_down(v, o);
    if ((tid & 63) == 0) sm[tid >> 6] = v;
    __syncthreads();
    return sm[0] + sm[1] + sm[2] + sm[3];
}

// ---------------- pass 1: column scale = sqrt(512)/||e(:,u)|| ----------------
__global__ __launch_bounds__(256) void prep_norm(const float* __restrict__ mu,
        const float* __restrict__ sigma, float* __restrict__ scale, int K) {
    __shared__ float sm[4];
    const int u = blockIdx.x, tid = threadIdx.x;
    const float m = mu[u];
    const float si = fminf(fmaxf(sigma[u], 0.01f), 1.0f);
    const float inv = 1.0f / (2.0f * si * si);
    const float inm1 = 1.0f / (float)(K - 1);
    float s = 0.f;
    for (int k = tid; k < K; k += 256) {
        const float x = k * inm1 - m;
        const float e = __expf(-x * x * inv);
        s += e * e;
    }
    s = blk_sum(s, sm, tid);
    if (tid == 0) scale[u] = sqrtf(512.0f) * __frsqrt_rn(s);
}

// ---------------- pass 2: K[k][u] = W[k][u]*e(k,u)*scale[u] (coalesced) ------
__global__ __launch_bounds__(256) void prep_apply(const float* __restrict__ W,
        const float* __restrict__ mu, const float* __restrict__ sigma,
        const float* __restrict__ scale, float* __restrict__ Kdst, int K) {
    const int k = blockIdx.x, tid = threadIdx.x;
    const int u = tid * 4;
    const float4 m4 = *(const float4*)&mu[u];
    const float4 sg4 = *(const float4*)&sigma[u];
    const float4 sc4 = *(const float4*)&scale[u];
    const float4 w4 = *(const float4*)&W[k * Uu + u];
    const float kk = k * (1.0f / (float)(K - 1));
    float4 o;
    {
        float si = fminf(fmaxf(sg4.x, 0.01f), 1.0f); float x = kk - m4.x;
        o.x = w4.x * __expf(-x * x / (2.f * si * si)) * sc4.x;
    }{
        float si = fminf(fmaxf(sg4.y, 0.01f), 1.0f); float x = kk - m4.y;
        o.y = w4.y * __expf(-x * x / (2.f * si * si)) * sc4.y;
    }{
        float si = fminf(fmaxf(sg4.z, 0.01f), 1.0f); float x = kk - m4.z;
        o.z = w4.z * __expf(-x * x / (2.f * si * si)) * sc4.z;
    }{
        float si = fminf(fmaxf(sg4.w, 0.01f), 1.0f); float x = kk - m4.w;
        o.w = w4.w * __expf(-x * x / (2.f * si * si)) * sc4.w;
    }
    *(float4*)&Kdst[k * Uu + u] = o;
}

// ---------------- xk = x @ Kc  (fp32 tiled GEMM) ----------------
__global__ __launch_bounds__(256) void gemm_xk(const float* __restrict__ A,
        const float* __restrict__ Bm, float* __restrict__ C) {
    __shared__ float As[16][64];
    __shared__ float Bs[16][64];
    const int tid = threadIdx.x;
    const int m0 = blockIdx.y * 64, n0 = blockIdx.x * 64;
    const int tm = tid >> 4, tn = tid & 15;
    const int a_m = tid >> 2, a_k = (tid & 3) << 2;
    const int b_k = tid >> 4, b_n = (tid & 15) << 2;
    float acc[4][4] = {};
    for (int kc = 0; kc < Dd; kc += 16) {
        const float4 av = *(const float4*)&A[(m0 + a_m) * Dd + kc + a_k];
        const float4 bv = *(const float4*)&Bm[(b_k + kc) * Uu + n0 + b_n];
        __syncthreads();
        As[a_k + 0][a_m] = av.x;
        As[a_k + 1][a_m] = av.y;
        As[a_k + 2][a_m] = av.z;
        As[a_k + 3][a_m] = av.w;
        *(float4*)&Bs[b_k][b_n] = bv;
        __syncthreads();
#pragma unroll
        for (int kk = 0; kk < 16; kk++) {
            const float4 a4 = *(const float4*)&As[kk][tm * 4];
            const float4 b4 = *(const float4*)&Bs[kk][tn * 4];
            acc[0][0] += a4.x * b4.x; acc[0][1] += a4.x * b4.y; acc[0][2] += a4.x * b4.z; acc[0][3] += a4.x * b4.w;
            acc[1][0] += a4.y * b4.x; acc[1][1] += a4.y * b4.y; acc[1][2] += a4.y * b4.z; acc[1][3] += a4.y * b4.w;
            acc[2][0] += a4.z * b4.x; acc[2][1] += a4.z * b4.y; acc[2][2] += a4.z * b4.z; acc[2][3] += a4.z * b4.w;
            acc[3][0] += a4.w * b4.x; acc[3][1] += a4.w * b4.y; acc[3][2] += a4.w * b4.z; acc[3][3] += a4.w * b4.w;
        }
    }
#pragma unroll
    for (int i = 0; i < 4; i++) {
        const float4 o = make_float4(acc[i][0], acc[i][1], acc[i][2], acc[i][3]);
        *(float4*)&C[(long)(m0 + tm * 4 + i) * Uu + n0 + tn * 4] = o;
    }
}

// ---------------- persistent recurrence ----------------
// 256 WGs x 256 threads, PLAIN launch (cooperative launch silently failed ->
// kernel never ran; bit-identical absmax across rounds 2/4/5 proved it).
// Co-residency: 1 WG/CU by resources (55KB LDS, ~300 VGPR/wave), grid=256=CUs,
// so all WGs dispatch immediately; spin-flag sync cannot starve.
// WG (bq,uq): b-rows [bq*4,+4), u-cols [uq*64,+64), full k=1024 in-CU.
// Thread (up=tid&7, kp=tid>>3): Kp[kp*32..+32)[u_base..+8) in 256 VGPRs.
// Cross-WG h exchange entirely through device-scope atomics (MALL-coherent).
#define HS_IDX(k, b) (((k) & 31) * 132 + ((k) >> 5) * 4 + (b))
#define RED_IDX(kp, up, e) ((kp) * 297 + (up) * 36 + (e))
#define FMA4(A, s, V) { (A).x += (s) * (V).x; (A).y += (s) * (V).y; (A).z += (s) * (V).z; (A).w += (s) * (V).w; }

__global__ __launch_bounds__(256, 1) void rnn_persistent(
        float* __restrict__ out, const float* __restrict__ h0,
        const float* __restrict__ Kp, unsigned int* __restrict__ cnt) {
    __shared__ float hs[32 * 132 + 128];      // 4352 floats
    __shared__ float red[32 * 297];           // 9504 floats
    const int tid = threadIdx.x;
    const int bq = blockIdx.x & 15;
    const int uq = blockIdx.x >> 4;
    const int b0 = bq * 4;
    const int up = tid & 7, kp = tid >> 3;
    const int u_base = uq * 64 + up * 8;

    // load Kp slice into registers (once; written by earlier kernel -> coherent)
    float4 kr[32][2];
#pragma unroll
    for (int ki = 0; ki < 32; ki++) {
        const float* p = Kp + (size_t)(kp * 32 + ki) * Uu + u_base;
        kr[ki][0] = *(const float4*)p;
        kr[ki][1] = *(const float4*)(p + 4);
    }

    unsigned int* mycnt = cnt + bq * 16;       // 64B-padded counter per b-group
    const int sr = tid >> 6;                   // staging: local b-row 0..3
    const int sc = tid & 63;                   // staging: f4-chunk lane

    for (int t = 0; t < Tt; t++) {
        // ---- stage h_prev rows b0..b0+3 into LDS ----
        if (t == 0) {
            const float* src = h0 + (size_t)(b0 + sr) * Uu;
#pragma unroll
            for (int j = 0; j < 4; j++) {
                const int c4 = sc + 64 * j;               // f4-chunk 0..255
                const float4 v = *(const float4*)&src[c4 * 4];
                const int k0 = c4 * 4;
                hs[HS_IDX(k0 + 0, sr)] = v.x; hs[HS_IDX(k0 + 1, sr)] = v.y;
                hs[HS_IDX(k0 + 2, sr)] = v.z; hs[HS_IDX(k0 + 3, sr)] = v.w;
            }
        } else {
            const float* src = out + ((size_t)(b0 + sr) * Tt + (t - 1)) * Uu;
#pragma unroll
            for (int j = 0; j < 4; j++) {
                const int c4 = sc + 64 * j;
                const float* base = src + c4 * 4;
                // device-scope atomic loads: served at the coherence point
                const float x0 = __hip_atomic_load(base + 0, __ATOMIC_RELAXED, __HIP_MEMORY_SCOPE_AGENT);
                const float x1 = __hip_atomic_load(base + 1, __ATOMIC_RELAXED, __HIP_MEMORY_SCOPE_AGENT);
                const float x2 = __hip_atomic_load(base + 2, __ATOMIC_RELAXED, __HIP_MEMORY_SCOPE_AGENT);
                const float x3 = __hip_atomic_load(base + 3, __ATOMIC_RELAXED, __HIP_MEMORY_SCOPE_AGENT);
                const int k0 = c4 * 4;
                hs[HS_IDX(k0 + 0, sr)] = x0; hs[HS_IDX(k0 + 1, sr)] = x1;
                hs[HS_IDX(k0 + 2, sr)] = x2; hs[HS_IDX(k0 + 3, sr)] = x3;
            }
        }
        __syncthreads();

        // ---- FMA: acc[4b][8u] over k in [kp*32,+32), Kp from registers ----
        float4 acc[4][2];
#pragma unroll
        for (int b = 0; b < 4; b++) { acc[b][0] = make_float4(0, 0, 0, 0); acc[b][1] = make_float4(0, 0, 0, 0); }
#pragma unroll
        for (int ki = 0; ki < 32; ki++) {
            const int k = kp * 32 + ki;
            const float4 h4 = *(const float4*)&hs[HS_IDX(k, 0)];
            const float4 ka = kr[ki][0], kb = kr[ki][1];
            FMA4(acc[0][0], h4.x, ka); FMA4(acc[0][1], h4.x, kb);
            FMA4(acc[1][0], h4.y, ka); FMA4(acc[1][1], h4.y, kb);
            FMA4(acc[2][0], h4.z, ka); FMA4(acc[2][1], h4.z, kb);
            FMA4(acc[3][0], h4.w, ka); FMA4(acc[3][1], h4.w, kb);
        }

        // ---- write partials to LDS ----
#pragma unroll
        for (int b = 0; b < 4; b++)
#pragma unroll
            for (int j = 0; j < 2; j++) {
                const int e = b * 8 + j * 4;
                red[RED_IDX(kp, up, e + 0)] = acc[b][j].x;
                red[RED_IDX(kp, up, e + 1)] = acc[b][j].y;
                red[RED_IDX(kp, up, e + 2)] = acc[b][j].z;
                red[RED_IDX(kp, up, e + 3)] = acc[b][j].w;
            }
        __syncthreads();

        // ---- reduce across kp; h_new = xk + sum via device-scope atomic add ----
        {
            const int b_loc = tid >> 6, u_loc = tid & 63;
            const int up2 = u_loc >> 3, e2 = b_loc * 8 + (u_loc & 7);
            float s = 0.f;
#pragma unroll
            for (int kk = 0; kk < 32; kk++) s += red[RED_IDX(kk, up2, e2)];
            const size_t o = ((size_t)(b0 + b_loc) * Tt + t) * Uu + uq * 64 + u_loc;
            // out holds xk_t (from gemm); RMW performed at the coherence point
            __hip_atomic_fetch_add(out + o, s, __ATOMIC_RELAXED, __HIP_MEMORY_SCOPE_AGENT);
        }
        __syncthreads();   // drains each thread's atomic before the flag

        // ---- b-group flag sync ----
        if (t < Tt - 1) {
            if (tid == 0) {
                __hip_atomic_fetch_add(mycnt, 1u, __ATOMIC_RELEASE, __HIP_MEMORY_SCOPE_AGENT);
                const unsigned int target = (unsigned int)(t + 1) * 16u;
                while (__hip_atomic_load(mycnt, __ATOMIC_ACQUIRE, __HIP_MEMORY_SCOPE_AGENT) < target) {}
            }
            __syncthreads();
        }
    }
}

extern "C" void kernel_launch(void* const* d_in, const int* in_sizes, int n_in,
                              void* d_out, int out_size, void* d_ws, size_t ws_size,
                              hipStream_t stream) {
    const float* x     = (const float*)d_in[0];
    const float* h0    = (const float*)d_in[1];
    const float* Wc    = (const float*)d_in[2];
    const float* Wp    = (const float*)d_in[3];
    const float* mu_c  = (const float*)d_in[4];
    const float* sig_c = (const float*)d_in[5];
    const float* mu_p  = (const float*)d_in[6];
    const float* sig_p = (const float*)d_in[7];
    float* out = (float*)d_out;

    float* Kc  = (float*)d_ws;               // 2 MB
    float* Kp  = Kc + (size_t)Dd * Uu;       // 4 MB
    unsigned int* cnt = (unsigned int*)d_ws; // overlaps Kc (dead after gemm)

    // scales stashed in tail of d_out (overwritten by gemm afterwards)
    float* scale_c = out + (size_t)out_size - 2048;
    float* scale_p = out + (size_t)out_size - 1024;

    prep_norm<<<dim3(Uu), dim3(256), 0, stream>>>(mu_c, sig_c, scale_c, Dd);
    prep_norm<<<dim3(Uu), dim3(256), 0, stream>>>(mu_p, sig_p, scale_p, Uu);
    prep_apply<<<dim3(Dd), dim3(256), 0, stream>>>(Wc, mu_c, sig_c, scale_c, Kc, Dd);
    prep_apply<<<dim3(Uu), dim3(256), 0, stream>>>(Wp, mu_p, sig_p, scale_p, Kp, Uu);

    gemm_xk<<<dim3(Uu / 64, (Bb * Tt) / 64), dim3(256), 0, stream>>>(x, Kc, out);

    // Kc is dead now; reuse its space for sync counters
    hipMemsetAsync(cnt, 0, 16 * 16 * sizeof(unsigned int), stream);

    // PLAIN launch (not cooperative): grid == 256 == #CUs, 1 WG/CU by resources.
    rnn_persistent<<<dim3(256), dim3(256), 0, stream>>>(out, h0, Kp, cnt);
}

// Round 7
// 2187.647 us; speedup vs baseline: 1.6543x; 1.0587x over previous
//
#include <hip/hip_runtime.h>

#define Tt 256
#define Uu 1024
#define Bb 64
#define Dd 512

// ---------------- block reduction helper ----------------
__device__ __forceinline__ float blk_sum(float v, float* sm, int tid) {
#pragma unroll
    for (int o = 32; o > 0; o >>= 1) v += __shfl_down(v, o);
    if ((tid & 63) == 0) sm[tid >> 6] = v;
    __syncthreads();
    return sm[0] + sm[1] + sm[2] + sm[3];
}

// ---------------- pass 1: column scale = sqrt(512)/||e(:,u)|| ----------------
__global__ __launch_bounds__(256) void prep_norm(const float* __restrict__ mu,
        const float* __restrict__ sigma, float* __restrict__ scale, int K) {
    __shared__ float sm[4];
    const int u = blockIdx.x, tid = threadIdx.x;
    const float m = mu[u];
    const float si = fminf(fmaxf(sigma[u], 0.01f), 1.0f);
    const float inv = 1.0f / (2.0f * si * si);
    const float inm1 = 1.0f / (float)(K - 1);
    float s = 0.f;
    for (int k = tid; k < K; k += 256) {
        const float x = k * inm1 - m;
        const float e = __expf(-x * x * inv);
        s += e * e;
    }
    s = blk_sum(s, sm, tid);
    if (tid == 0) scale[u] = sqrtf(512.0f) * __frsqrt_rn(s);
}

// ---------------- pass 2: K[k][u] = W[k][u]*e(k,u)*scale[u] (coalesced) ------
__global__ __launch_bounds__(256) void prep_apply(const float* __restrict__ W,
        const float* __restrict__ mu, const float* __restrict__ sigma,
        const float* __restrict__ scale, float* __restrict__ Kdst, int K) {
    const int k = blockIdx.x, tid = threadIdx.x;
    const int u = tid * 4;
    const float4 m4 = *(const float4*)&mu[u];
    const float4 sg4 = *(const float4*)&sigma[u];
    const float4 sc4 = *(const float4*)&scale[u];
    const float4 w4 = *(const float4*)&W[k * Uu + u];
    const float kk = k * (1.0f / (float)(K - 1));
    float4 o;
    {
        float si = fminf(fmaxf(sg4.x, 0.01f), 1.0f); float x = kk - m4.x;
        o.x = w4.x * __expf(-x * x / (2.f * si * si)) * sc4.x;
    }{
        float si = fminf(fmaxf(sg4.y, 0.01f), 1.0f); float x = kk - m4.y;
        o.y = w4.y * __expf(-x * x / (2.f * si * si)) * sc4.y;
    }{
        float si = fminf(fmaxf(sg4.z, 0.01f), 1.0f); float x = kk - m4.z;
        o.z = w4.z * __expf(-x * x / (2.f * si * si)) * sc4.z;
    }{
        float si = fminf(fmaxf(sg4.w, 0.01f), 1.0f); float x = kk - m4.w;
        o.w = w4.w * __expf(-x * x / (2.f * si * si)) * sc4.w;
    }
    *(float4*)&Kdst[k * Uu + u] = o;
}

// ---------------- xk = x @ Kc  (fp32 tiled GEMM) ----------------
__global__ __launch_bounds__(256) void gemm_xk(const float* __restrict__ A,
        const float* __restrict__ Bm, float* __restrict__ C) {
    __shared__ float As[16][64];
    __shared__ float Bs[16][64];
    const int tid = threadIdx.x;
    const int m0 = blockIdx.y * 64, n0 = blockIdx.x * 64;
    const int tm = tid >> 4, tn = tid & 15;
    const int a_m = tid >> 2, a_k = (tid & 3) << 2;
    const int b_k = tid >> 4, b_n = (tid & 15) << 2;
    float acc[4][4] = {};
    for (int kc = 0; kc < Dd; kc += 16) {
        const float4 av = *(const float4*)&A[(m0 + a_m) * Dd + kc + a_k];
        const float4 bv = *(const float4*)&Bm[(b_k + kc) * Uu + n0 + b_n];
        __syncthreads();
        As[a_k + 0][a_m] = av.x;
        As[a_k + 1][a_m] = av.y;
        As[a_k + 2][a_m] = av.z;
        As[a_k + 3][a_m] = av.w;
        *(float4*)&Bs[b_k][b_n] = bv;
        __syncthreads();
#pragma unroll
        for (int kk = 0; kk < 16; kk++) {
            const float4 a4 = *(const float4*)&As[kk][tm * 4];
            const float4 b4 = *(const float4*)&Bs[kk][tn * 4];
            acc[0][0] += a4.x * b4.x; acc[0][1] += a4.x * b4.y; acc[0][2] += a4.x * b4.z; acc[0][3] += a4.x * b4.w;
            acc[1][0] += a4.y * b4.x; acc[1][1] += a4.y * b4.y; acc[1][2] += a4.y * b4.z; acc[1][3] += a4.y * b4.w;
            acc[2][0] += a4.z * b4.x; acc[2][1] += a4.z * b4.y; acc[2][2] += a4.z * b4.z; acc[2][3] += a4.z * b4.w;
            acc[3][0] += a4.w * b4.x; acc[3][1] += a4.w * b4.y; acc[3][2] += a4.w * b4.z; acc[3][3] += a4.w * b4.w;
        }
    }
#pragma unroll
    for (int i = 0; i < 4; i++) {
        const float4 o = make_float4(acc[i][0], acc[i][1], acc[i][2], acc[i][3]);
        *(float4*)&C[(long)(m0 + tm * 4 + i) * Uu + n0 + tn * 4] = o;
    }
}

// ---- coherent pipelined staging load: 4x dwordx4, L1/L2-bypass (sc0 sc1),
// one vmcnt(0). Served at the coherence point -> sees prior atomicAdd data. ----
__device__ __forceinline__ void stage_load4(const float* base,
        float4& v0, float4& v1, float4& v2, float4& v3) {
    asm volatile(
        "global_load_dwordx4 %0, %4, off sc0 sc1\n\t"
        "global_load_dwordx4 %1, %4, off offset:1024 sc0 sc1\n\t"
        "global_load_dwordx4 %2, %4, off offset:2048 sc0 sc1\n\t"
        "global_load_dwordx4 %3, %4, off offset:3072 sc0 sc1\n\t"
        "s_waitcnt vmcnt(0)"
        : "=&v"(v0), "=&v"(v1), "=&v"(v2), "=&v"(v3)
        : "v"(base)
        : "memory");
}

// ---------------- persistent recurrence ----------------
// 256 WGs x 256 threads, PLAIN launch. 1 WG/CU by resources (55KB LDS),
// grid=256=#CUs -> all WGs resident; spin-flag sync cannot starve.
// WG (bq,uq): b-rows [bq*4,+4), u-cols [uq*64,+64), full k=1024 in-CU.
// Thread (up=tid&7, kp=tid>>3): Kp[kp*32..+32)[u_base..+8) in 256 VGPRs.
// h exchange: writers atomicAdd (RMW at MALL), readers sc0sc1 vector loads.
#define HS_IDX(k, b) (((k) & 31) * 132 + ((k) >> 5) * 4 + (b))
#define RED_IDX(kp, up, e) ((kp) * 297 + (up) * 36 + (e))
#define FMA4(A, s, V) { (A).x += (s) * (V).x; (A).y += (s) * (V).y; (A).z += (s) * (V).z; (A).w += (s) * (V).w; }

__global__ __launch_bounds__(256, 1) void rnn_persistent(
        float* __restrict__ out, const float* __restrict__ h0,
        const float* __restrict__ Kp, unsigned int* __restrict__ cnt) {
    __shared__ float hs[32 * 132 + 128];      // 4352 floats
    __shared__ float red[32 * 297];           // 9504 floats
    const int tid = threadIdx.x;
    const int bq = blockIdx.x & 15;
    const int uq = blockIdx.x >> 4;
    const int b0 = bq * 4;
    const int up = tid & 7, kp = tid >> 3;
    const int u_base = uq * 64 + up * 8;

    // load Kp slice into registers (once; written by earlier kernel -> coherent)
    float4 kr[32][2];
#pragma unroll
    for (int ki = 0; ki < 32; ki++) {
        const float* p = Kp + (size_t)(kp * 32 + ki) * Uu + u_base;
        kr[ki][0] = *(const float4*)p;
        kr[ki][1] = *(const float4*)(p + 4);
    }

    unsigned int* mycnt = cnt + bq * 16;       // 64B-padded counter per b-group
    const int sr = tid >> 6;                   // staging: local b-row 0..3
    const int sc = tid & 63;                   // staging: f4-chunk lane

    for (int t = 0; t < Tt; t++) {
        // ---- stage h_prev rows b0..b0+3 into LDS ----
        {
            const float* src = (t == 0)
                ? h0 + (size_t)(b0 + sr) * Uu
                : out + ((size_t)(b0 + sr) * Tt + (t - 1)) * Uu;
            const float* base = src + sc * 4;   // chunks sc, sc+64, sc+128, sc+192
            float4 v0, v1, v2, v3;
            stage_load4(base, v0, v1, v2, v3);
            const int k0 = sc * 4;
            hs[HS_IDX(k0 + 0, sr)] = v0.x; hs[HS_IDX(k0 + 1, sr)] = v0.y;
            hs[HS_IDX(k0 + 2, sr)] = v0.z; hs[HS_IDX(k0 + 3, sr)] = v0.w;
            hs[HS_IDX(k0 + 256, sr)] = v1.x; hs[HS_IDX(k0 + 257, sr)] = v1.y;
            hs[HS_IDX(k0 + 258, sr)] = v1.z; hs[HS_IDX(k0 + 259, sr)] = v1.w;
            hs[HS_IDX(k0 + 512, sr)] = v2.x; hs[HS_IDX(k0 + 513, sr)] = v2.y;
            hs[HS_IDX(k0 + 514, sr)] = v2.z; hs[HS_IDX(k0 + 515, sr)] = v2.w;
            hs[HS_IDX(k0 + 768, sr)] = v3.x; hs[HS_IDX(k0 + 769, sr)] = v3.y;
            hs[HS_IDX(k0 + 770, sr)] = v3.z; hs[HS_IDX(k0 + 771, sr)] = v3.w;
        }
        __syncthreads();

        // ---- FMA: acc[4b][8u] over k in [kp*32,+32), Kp from registers ----
        float4 acc[4][2];
#pragma unroll
        for (int b = 0; b < 4; b++) { acc[b][0] = make_float4(0, 0, 0, 0); acc[b][1] = make_float4(0, 0, 0, 0); }
#pragma unroll
        for (int ki = 0; ki < 32; ki++) {
            const int k = kp * 32 + ki;
            const float4 h4 = *(const float4*)&hs[HS_IDX(k, 0)];
            const float4 ka = kr[ki][0], kb = kr[ki][1];
            FMA4(acc[0][0], h4.x, ka); FMA4(acc[0][1], h4.x, kb);
            FMA4(acc[1][0], h4.y, ka); FMA4(acc[1][1], h4.y, kb);
            FMA4(acc[2][0], h4.z, ka); FMA4(acc[2][1], h4.z, kb);
            FMA4(acc[3][0], h4.w, ka); FMA4(acc[3][1], h4.w, kb);
        }

        // ---- write partials to LDS ----
#pragma unroll
        for (int b = 0; b < 4; b++)
#pragma unroll
            for (int j = 0; j < 2; j++) {
                const int e = b * 8 + j * 4;
                red[RED_IDX(kp, up, e + 0)] = acc[b][j].x;
                red[RED_IDX(kp, up, e + 1)] = acc[b][j].y;
                red[RED_IDX(kp, up, e + 2)] = acc[b][j].z;
                red[RED_IDX(kp, up, e + 3)] = acc[b][j].w;
            }
        __syncthreads();

        // ---- reduce across kp; h_new = xk + sum via device-scope atomic add ----
        {
            const int b_loc = tid >> 6, u_loc = tid & 63;
            const int up2 = u_loc >> 3, e2 = b_loc * 8 + (u_loc & 7);
            float s = 0.f;
#pragma unroll
            for (int kk = 0; kk < 32; kk++) s += red[RED_IDX(kk, up2, e2)];
            const size_t o = ((size_t)(b0 + b_loc) * Tt + t) * Uu + uq * 64 + u_loc;
            // out holds xk_t (from gemm); RMW performed at the coherence point
            __hip_atomic_fetch_add(out + o, s, __ATOMIC_RELAXED, __HIP_MEMORY_SCOPE_AGENT);
        }
        __syncthreads();   // drains each thread's atomic before the flag

        // ---- b-group flag sync ----
        if (t < Tt - 1) {
            if (tid == 0) {
                __hip_atomic_fetch_add(mycnt, 1u, __ATOMIC_RELEASE, __HIP_MEMORY_SCOPE_AGENT);
                const unsigned int target = (unsigned int)(t + 1) * 16u;
                while (__hip_atomic_load(mycnt, __ATOMIC_ACQUIRE, __HIP_MEMORY_SCOPE_AGENT) < target) {}
            }
            __syncthreads();
        }
    }
}

extern "C" void kernel_launch(void* const* d_in, const int* in_sizes, int n_in,
                              void* d_out, int out_size, void* d_ws, size_t ws_size,
                              hipStream_t stream) {
    const float* x     = (const float*)d_in[0];
    const float* h0    = (const float*)d_in[1];
    const float* Wc    = (const float*)d_in[2];
    const float* Wp    = (const float*)d_in[3];
    const float* mu_c  = (const float*)d_in[4];
    const float* sig_c = (const float*)d_in[5];
    const float* mu_p  = (const float*)d_in[6];
    const float* sig_p = (const float*)d_in[7];
    float* out = (float*)d_out;

    float* Kc  = (float*)d_ws;               // 2 MB
    float* Kp  = Kc + (size_t)Dd * Uu;       // 4 MB
    unsigned int* cnt = (unsigned int*)d_ws; // overlaps Kc (dead after gemm)

    // scales stashed in tail of d_out (overwritten by gemm afterwards)
    float* scale_c = out + (size_t)out_size - 2048;
    float* scale_p = out + (size_t)out_size - 1024;

    prep_norm<<<dim3(Uu), dim3(256), 0, stream>>>(mu_c, sig_c, scale_c, Dd);
    prep_norm<<<dim3(Uu), dim3(256), 0, stream>>>(mu_p, sig_p, scale_p, Uu);
    prep_apply<<<dim3(Dd), dim3(256), 0, stream>>>(Wc, mu_c, sig_c, scale_c, Kc, Dd);
    prep_apply<<<dim3(Uu), dim3(256), 0, stream>>>(Wp, mu_p, sig_p, scale_p, Kp, Uu);

    gemm_xk<<<dim3(Uu / 64, (Bb * Tt) / 64), dim3(256), 0, stream>>>(x, Kc, out);

    // Kc is dead now; reuse its space for sync counters
    hipMemsetAsync(cnt, 0, 16 * 16 * sizeof(unsigned int), stream);

    // PLAIN launch (not cooperative): grid == 256 == #CUs, 1 WG/CU by resources.
    rnn_persistent<<<dim3(256), dim3(256), 0, stream>>>(out, h0, Kp, cnt);
}

// Round 8
// 2184.352 us; speedup vs baseline: 1.6567x; 1.0015x over previous
//
#include <hip/hip_runtime.h>

#define Tt 256
#define Uu 1024
#define Bb 64
#define Dd 512

// ---------------- block reduction helper ----------------
__device__ __forceinline__ float blk_sum(float v, float* sm, int tid) {
#pragma unroll
    for (int o = 32; o > 0; o >>= 1) v += __shfl_down(v, o);
    if ((tid & 63) == 0) sm[tid >> 6] = v;
    __syncthreads();
    return sm[0] + sm[1] + sm[2] + sm[3];
}

// ---------------- pass 1: column scale = sqrt(512)/||e(:,u)|| ----------------
__global__ __launch_bounds__(256) void prep_norm(const float* __restrict__ mu,
        const float* __restrict__ sigma, float* __restrict__ scale, int K) {
    __shared__ float sm[4];
    const int u = blockIdx.x, tid = threadIdx.x;
    const float m = mu[u];
    const float si = fminf(fmaxf(sigma[u], 0.01f), 1.0f);
    const float inv = 1.0f / (2.0f * si * si);
    const float inm1 = 1.0f / (float)(K - 1);
    float s = 0.f;
    for (int k = tid; k < K; k += 256) {
        const float x = k * inm1 - m;
        const float e = __expf(-x * x * inv);
        s += e * e;
    }
    s = blk_sum(s, sm, tid);
    if (tid == 0) scale[u] = sqrtf(512.0f) * __frsqrt_rn(s);
}

// ---------------- pass 2: K[k][u] = W[k][u]*e(k,u)*scale[u] (coalesced) ------
__global__ __launch_bounds__(256) void prep_apply(const float* __restrict__ W,
        const float* __restrict__ mu, const float* __restrict__ sigma,
        const float* __restrict__ scale, float* __restrict__ Kdst, int K) {
    const int k = blockIdx.x, tid = threadIdx.x;
    const int u = tid * 4;
    const float4 m4 = *(const float4*)&mu[u];
    const float4 sg4 = *(const float4*)&sigma[u];
    const float4 sc4 = *(const float4*)&scale[u];
    const float4 w4 = *(const float4*)&W[k * Uu + u];
    const float kk = k * (1.0f / (float)(K - 1));
    float4 o;
    {
        float si = fminf(fmaxf(sg4.x, 0.01f), 1.0f); float x = kk - m4.x;
        o.x = w4.x * __expf(-x * x / (2.f * si * si)) * sc4.x;
    }{
        float si = fminf(fmaxf(sg4.y, 0.01f), 1.0f); float x = kk - m4.y;
        o.y = w4.y * __expf(-x * x / (2.f * si * si)) * sc4.y;
    }{
        float si = fminf(fmaxf(sg4.z, 0.01f), 1.0f); float x = kk - m4.z;
        o.z = w4.z * __expf(-x * x / (2.f * si * si)) * sc4.z;
    }{
        float si = fminf(fmaxf(sg4.w, 0.01f), 1.0f); float x = kk - m4.w;
        o.w = w4.w * __expf(-x * x / (2.f * si * si)) * sc4.w;
    }
    *(float4*)&Kdst[k * Uu + u] = o;
}

// ---------------- xk = x @ Kc  (fp32 tiled GEMM) ----------------
__global__ __launch_bounds__(256) void gemm_xk(const float* __restrict__ A,
        const float* __restrict__ Bm, float* __restrict__ C) {
    __shared__ float As[16][64];
    __shared__ float Bs[16][64];
    const int tid = threadIdx.x;
    const int m0 = blockIdx.y * 64, n0 = blockIdx.x * 64;
    const int tm = tid >> 4, tn = tid & 15;
    const int a_m = tid >> 2, a_k = (tid & 3) << 2;
    const int b_k = tid >> 4, b_n = (tid & 15) << 2;
    float acc[4][4] = {};
    for (int kc = 0; kc < Dd; kc += 16) {
        const float4 av = *(const float4*)&A[(m0 + a_m) * Dd + kc + a_k];
        const float4 bv = *(const float4*)&Bm[(b_k + kc) * Uu + n0 + b_n];
        __syncthreads();
        As[a_k + 0][a_m] = av.x;
        As[a_k + 1][a_m] = av.y;
        As[a_k + 2][a_m] = av.z;
        As[a_k + 3][a_m] = av.w;
        *(float4*)&Bs[b_k][b_n] = bv;
        __syncthreads();
#pragma unroll
        for (int kk = 0; kk < 16; kk++) {
            const float4 a4 = *(const float4*)&As[kk][tm * 4];
            const float4 b4 = *(const float4*)&Bs[kk][tn * 4];
            acc[0][0] += a4.x * b4.x; acc[0][1] += a4.x * b4.y; acc[0][2] += a4.x * b4.z; acc[0][3] += a4.x * b4.w;
            acc[1][0] += a4.y * b4.x; acc[1][1] += a4.y * b4.y; acc[1][2] += a4.y * b4.z; acc[1][3] += a4.y * b4.w;
            acc[2][0] += a4.z * b4.x; acc[2][1] += a4.z * b4.y; acc[2][2] += a4.z * b4.z; acc[2][3] += a4.z * b4.w;
            acc[3][0] += a4.w * b4.x; acc[3][1] += a4.w * b4.y; acc[3][2] += a4.w * b4.z; acc[3][3] += a4.w * b4.w;
        }
    }
#pragma unroll
    for (int i = 0; i < 4; i++) {
        const float4 o = make_float4(acc[i][0], acc[i][1], acc[i][2], acc[i][3]);
        *(float4*)&C[(long)(m0 + tm * 4 + i) * Uu + n0 + tn * 4] = o;
    }
}

// ---- coherent pipelined staging load: 4x dwordx4, L1/L2-bypass (sc0 sc1),
// one vmcnt(0). Served at the coherence point -> sees prior atomicAdd data. ----
__device__ __forceinline__ void stage_load4(const float* base,
        float4& v0, float4& v1, float4& v2, float4& v3) {
    asm volatile(
        "global_load_dwordx4 %0, %4, off sc0 sc1\n\t"
        "global_load_dwordx4 %1, %4, off offset:1024 sc0 sc1\n\t"
        "global_load_dwordx4 %2, %4, off offset:2048 sc0 sc1\n\t"
        "global_load_dwordx4 %3, %4, off offset:3072 sc0 sc1\n\t"
        "s_waitcnt vmcnt(0)"
        : "=&v"(v0), "=&v"(v1), "=&v"(v2), "=&v"(v3)
        : "v"(base)
        : "memory");
}

// ---------------- persistent recurrence ----------------
// 256 WGs x 256 threads, PLAIN launch, 1 WG/CU (grid == #CUs).
// amdgpu_waves_per_eu(1,1): force single-wave-per-SIMD register budget (512
// VGPR) so the 256-float kr[] Kp slice ACTUALLY resides in VGPRs. Round 7's
// VGPR_Count=208 < 256 proved the compiler was NOT keeping it resident
// (re-streaming Kp from L2 every step, ~10k cy/step — the dominant cost).
#define HS_IDX(k, b) (((k) & 31) * 132 + ((k) >> 5) * 4 + (b))
#define RED_IDX(kp, up, e) ((kp) * 297 + (up) * 36 + (e))
#define FMA4(A, s, V) { (A).x += (s) * (V).x; (A).y += (s) * (V).y; (A).z += (s) * (V).z; (A).w += (s) * (V).w; }

__global__ __attribute__((amdgpu_flat_work_group_size(256, 256)))
__attribute__((amdgpu_waves_per_eu(1, 1))) void rnn_persistent(
        float* __restrict__ out, const float* __restrict__ h0,
        const float* __restrict__ Kp, unsigned int* __restrict__ cnt) {
    __shared__ float hs[32 * 132 + 128];      // 4352 floats
    __shared__ float red[32 * 297];           // 9504 floats
    const int tid = threadIdx.x;
    const int bq = blockIdx.x & 15;
    const int uq = blockIdx.x >> 4;
    const int b0 = bq * 4;
    const int up = tid & 7, kp = tid >> 3;
    const int u_base = uq * 64 + up * 8;

    // load Kp slice into registers (once; written by earlier kernel -> coherent)
    float4 kr[32][2];
#pragma unroll
    for (int ki = 0; ki < 32; ki++) {
        const float* p = Kp + (size_t)(kp * 32 + ki) * Uu + u_base;
        kr[ki][0] = *(const float4*)p;
        kr[ki][1] = *(const float4*)(p + 4);
    }

    unsigned int* mycnt = cnt + bq * 16;       // 64B-padded counter per b-group
    const int sr = tid >> 6;                   // staging: local b-row 0..3
    const int sc = tid & 63;                   // staging: f4-chunk lane

    for (int t = 0; t < Tt; t++) {
        // ---- stage h_prev rows b0..b0+3 into LDS ----
        {
            const float* src = (t == 0)
                ? h0 + (size_t)(b0 + sr) * Uu
                : out + ((size_t)(b0 + sr) * Tt + (t - 1)) * Uu;
            const float* base = src + sc * 4;   // chunks sc, sc+64, sc+128, sc+192
            float4 v0, v1, v2, v3;
            stage_load4(base, v0, v1, v2, v3);
            const int k0 = sc * 4;
            hs[HS_IDX(k0 + 0, sr)] = v0.x; hs[HS_IDX(k0 + 1, sr)] = v0.y;
            hs[HS_IDX(k0 + 2, sr)] = v0.z; hs[HS_IDX(k0 + 3, sr)] = v0.w;
            hs[HS_IDX(k0 + 256, sr)] = v1.x; hs[HS_IDX(k0 + 257, sr)] = v1.y;
            hs[HS_IDX(k0 + 258, sr)] = v1.z; hs[HS_IDX(k0 + 259, sr)] = v1.w;
            hs[HS_IDX(k0 + 512, sr)] = v2.x; hs[HS_IDX(k0 + 513, sr)] = v2.y;
            hs[HS_IDX(k0 + 514, sr)] = v2.z; hs[HS_IDX(k0 + 515, sr)] = v2.w;
            hs[HS_IDX(k0 + 768, sr)] = v3.x; hs[HS_IDX(k0 + 769, sr)] = v3.y;
            hs[HS_IDX(k0 + 770, sr)] = v3.z; hs[HS_IDX(k0 + 771, sr)] = v3.w;
        }
        __syncthreads();

        // ---- FMA: acc[4b][8u] over k in [kp*32,+32), Kp from registers ----
        float4 acc[4][2];
#pragma unroll
        for (int b = 0; b < 4; b++) { acc[b][0] = make_float4(0, 0, 0, 0); acc[b][1] = make_float4(0, 0, 0, 0); }
#pragma unroll
        for (int ki = 0; ki < 32; ki++) {
            const int k = kp * 32 + ki;
            const float4 h4 = *(const float4*)&hs[HS_IDX(k, 0)];
            const float4 ka = kr[ki][0], kb = kr[ki][1];
            FMA4(acc[0][0], h4.x, ka); FMA4(acc[0][1], h4.x, kb);
            FMA4(acc[1][0], h4.y, ka); FMA4(acc[1][1], h4.y, kb);
            FMA4(acc[2][0], h4.z, ka); FMA4(acc[2][1], h4.z, kb);
            FMA4(acc[3][0], h4.w, ka); FMA4(acc[3][1], h4.w, kb);
        }

        // ---- write partials to LDS ----
#pragma unroll
        for (int b = 0; b < 4; b++)
#pragma unroll
            for (int j = 0; j < 2; j++) {
                const int e = b * 8 + j * 4;
                red[RED_IDX(kp, up, e + 0)] = acc[b][j].x;
                red[RED_IDX(kp, up, e + 1)] = acc[b][j].y;
                red[RED_IDX(kp, up, e + 2)] = acc[b][j].z;
                red[RED_IDX(kp, up, e + 3)] = acc[b][j].w;
            }
        __syncthreads();

        // ---- reduce across kp; h_new = xk + sum via device-scope atomic add ----
        {
            const int b_loc = tid >> 6, u_loc = tid & 63;
            const int up2 = u_loc >> 3, e2 = b_loc * 8 + (u_loc & 7);
            float s = 0.f;
#pragma unroll
            for (int kk = 0; kk < 32; kk++) s += red[RED_IDX(kk, up2, e2)];
            const size_t o = ((size_t)(b0 + b_loc) * Tt + t) * Uu + uq * 64 + u_loc;
            // out holds xk_t (from gemm); RMW performed at the coherence point
            __hip_atomic_fetch_add(out + o, s, __ATOMIC_RELAXED, __HIP_MEMORY_SCOPE_AGENT);
        }
        __syncthreads();   // drains each thread's atomic before the flag

        // ---- b-group flag sync ----
        if (t < Tt - 1) {
            if (tid == 0) {
                __hip_atomic_fetch_add(mycnt, 1u, __ATOMIC_RELEASE, __HIP_MEMORY_SCOPE_AGENT);
                const unsigned int target = (unsigned int)(t + 1) * 16u;
                while (__hip_atomic_load(mycnt, __ATOMIC_ACQUIRE, __HIP_MEMORY_SCOPE_AGENT) < target) {}
            }
            __syncthreads();
        }
    }
}

extern "C" void kernel_launch(void* const* d_in, const int* in_sizes, int n_in,
                              void* d_out, int out_size, void* d_ws, size_t ws_size,
                              hipStream_t stream) {
    const float* x     = (const float*)d_in[0];
    const float* h0    = (const float*)d_in[1];
    const float* Wc    = (const float*)d_in[2];
    const float* Wp    = (const float*)d_in[3];
    const float* mu_c  = (const float*)d_in[4];
    const float* sig_c = (const float*)d_in[5];
    const float* mu_p  = (const float*)d_in[6];
    const float* sig_p = (const float*)d_in[7];
    float* out = (float*)d_out;

    float* Kc  = (float*)d_ws;               // 2 MB
    float* Kp  = Kc + (size_t)Dd * Uu;       // 4 MB
    unsigned int* cnt = (unsigned int*)d_ws; // overlaps Kc (dead after gemm)

    // scales stashed in tail of d_out (overwritten by gemm afterwards)
    float* scale_c = out + (size_t)out_size - 2048;
    float* scale_p = out + (size_t)out_size - 1024;

    prep_norm<<<dim3(Uu), dim3(256), 0, stream>>>(mu_c, sig_c, scale_c, Dd);
    prep_norm<<<dim3(Uu), dim3(256), 0, stream>>>(mu_p, sig_p, scale_p, Uu);
    prep_apply<<<dim3(Dd), dim3(256), 0, stream>>>(Wc, mu_c, sig_c, scale_c, Kc, Dd);
    prep_apply<<<dim3(Uu), dim3(256), 0, stream>>>(Wp, mu_p, sig_p, scale_p, Kp, Uu);

    gemm_xk<<<dim3(Uu / 64, (Bb * Tt) / 64), dim3(256), 0, stream>>>(x, Kc, out);

    // Kc is dead now; reuse its space for sync counters
    hipMemsetAsync(cnt, 0, 16 * 16 * sizeof(unsigned int), stream);

    // PLAIN launch (not cooperative): grid == 256 == #CUs, 1 WG/CU by resources.
    rnn_persistent<<<dim3(256), dim3(256), 0, stream>>>(out, h0, Kp, cnt);
}